// Round 1
// baseline (2782.091 us; speedup 1.0000x reference)
//
#include <hip/hip_runtime.h>
#include <cstdint>

// Problem constants (fixed by the reference)
#define NN   50000          // global nodes
#define SS   2048           // subgraphs
#define KSUB 64             // nodes per subgraph
#define HH   128            // hidden dim (== C)
#define EE   (SS * 256)     // total edges (uniform 256/subgraph)
#define SKK  (SS * KSUB)    // 131072 flat rows
#define LLAY 5

// ---------------------------------------------------------------------------
// Fold node_proj/logp_proj/root_emb through init_proj (exact linear algebra):
// h = gx@(Wn@Wi_a) + lp*(wl@Wi_b) + (bn@Wi_a + bl@Wi_b + bi) + root_emb[r]@Wi_c
// ---------------------------------------------------------------------------
__global__ void fold_M_k(const float* __restrict__ Wn, const float* __restrict__ Wi,
                         float* __restrict__ M) {
  int c = blockIdx.x, n = threadIdx.x;
  float s = 0.f;
  for (int k = 0; k < HH; ++k) s = fmaf(Wn[c * HH + k], Wi[k * HH + n], s);
  M[c * HH + n] = s;
}

__global__ void fold_vec_k(const float* __restrict__ Wi, const float* __restrict__ wl,
                           const float* __restrict__ bnb, const float* __restrict__ blb,
                           const float* __restrict__ bi, const float* __restrict__ remb,
                           float* __restrict__ vl, float* __restrict__ c0,
                           float* __restrict__ rev) {
  int n = threadIdx.x;
  float svl = 0.f, sc0 = bi[n], r0 = 0.f, r1 = 0.f;
  for (int k = 0; k < HH; ++k) {
    svl = fmaf(wl[k], Wi[(HH + k) * HH + n], svl);
    sc0 = fmaf(bnb[k], Wi[k * HH + n], sc0);
    sc0 = fmaf(blb[k], Wi[(HH + k) * HH + n], sc0);
    r0  = fmaf(remb[k],      Wi[(2 * HH + k) * HH + n], r0);
    r1  = fmaf(remb[HH + k], Wi[(2 * HH + k) * HH + n], r1);
  }
  vl[n] = svl; c0[n] = sc0; rev[n] = r0; rev[HH + n] = r1;
}

// ---------------------------------------------------------------------------
// Valid-node counts per global node (all ids >= 0 for these inputs)
// ---------------------------------------------------------------------------
__global__ void count_k(const int* __restrict__ idc, int* __restrict__ cnt) {
  int i = blockIdx.x * 256 + threadIdx.x;
  if (i < SKK) atomicAdd(&cnt[idc[i]], 1);
}
__global__ void invert_k(const int* __restrict__ cnt, float* __restrict__ inv) {
  int i = blockIdx.x * 256 + threadIdx.x;
  if (i < NN) inv[i] = 1.0f / (float)max(cnt[i], 1);
}

// ---------------------------------------------------------------------------
// Per-subgraph counting sort of edges by dst -> CSR (edges are intra-subgraph)
// row_ptr has SKK+1 entries; sorted_src holds local src ids.
// ---------------------------------------------------------------------------
__launch_bounds__(256)
__global__ void presort_k(const int* __restrict__ e_src, const int* __restrict__ e_dst,
                          const int* __restrict__ edge_ptr, int* __restrict__ row_ptr,
                          int* __restrict__ ssrc) {
  __shared__ int cnt[KSUB];
  __shared__ int base[KSUB];
  __shared__ int cur[KSUB];
  const int s = blockIdx.x, tid = threadIdx.x;
  const int p0 = edge_ptr[s], p1 = edge_ptr[s + 1];
  if (tid < KSUB) cnt[tid] = 0;
  __syncthreads();
  for (int e = p0 + tid; e < p1; e += 256) atomicAdd(&cnt[e_dst[e]], 1);
  __syncthreads();
  if (tid == 0) {
    int a = 0;
    for (int d = 0; d < KSUB; ++d) { base[d] = a; a += cnt[d]; }
  }
  __syncthreads();
  if (tid < KSUB) { row_ptr[s * KSUB + tid] = p0 + base[tid]; cur[tid] = base[tid]; }
  if (s == 0 && tid == 0) row_ptr[SS * KSUB] = edge_ptr[SS];
  __syncthreads();
  for (int e = p0 + tid; e < p1; e += 256) {
    int d = e_dst[e];
    int pos = atomicAdd(&cur[d], 1);
    ssrc[p0 + pos] = e_src[e];
  }
}

// ---------------------------------------------------------------------------
// GIN aggregate: z0 = (1+eps)*h + sum_{j->i} h_j   (per subgraph, in LDS)
// hl stride 132 floats (= 33*16B, keeps float4 alignment, spreads banks)
// ---------------------------------------------------------------------------
__launch_bounds__(256)
__global__ void gin_agg_k(const float* __restrict__ h, const int* __restrict__ row_ptr,
                          const int* __restrict__ ssrc, const float* __restrict__ gin_eps,
                          const int layer, float* __restrict__ z0) {
  __shared__ __align__(16) float hl[KSUB * 132];
  const int s = blockIdx.x, tid = threadIdx.x;
  const float* hs = h + (size_t)s * KSUB * HH;
#pragma unroll
  for (int it = 0; it < 8; ++it) {
    int idx = it * 1024 + tid * 4;
    int m = idx >> 7, c = idx & 127;
    *(float4*)&hl[m * 132 + c] = *(const float4*)&hs[idx];
  }
  __syncthreads();
  const float ep1 = 1.0f + gin_eps[layer];
  const int d = tid >> 2, cg = (tid & 3) * 32;
  const int g = s * KSUB + d;
  const int e0 = row_ptr[g], e1 = row_ptr[g + 1];
  float a[32];
  const float* hp0 = &hl[d * 132 + cg];
#pragma unroll
  for (int j = 0; j < 8; ++j) {
    float4 v = *(const float4*)(hp0 + 4 * j);
    a[4 * j + 0] = ep1 * v.x; a[4 * j + 1] = ep1 * v.y;
    a[4 * j + 2] = ep1 * v.z; a[4 * j + 3] = ep1 * v.w;
  }
  for (int e = e0; e < e1; ++e) {
    const float* hp = &hl[ssrc[e] * 132 + cg];
#pragma unroll
    for (int j = 0; j < 8; ++j) {
      float4 v = *(const float4*)(hp + 4 * j);
      a[4 * j + 0] += v.x; a[4 * j + 1] += v.y;
      a[4 * j + 2] += v.z; a[4 * j + 3] += v.w;
    }
  }
  float* zp = z0 + (size_t)g * HH + cg;
#pragma unroll
  for (int j = 0; j < 8; ++j)
    *(float4*)(zp + 4 * j) = make_float4(a[4 * j], a[4 * j + 1], a[4 * j + 2], a[4 * j + 3]);
}

// ---------------------------------------------------------------------------
// Tiled fp32 GEMM, BM=64 BN=128 BK=32, 256 threads, 4x8 micro-tile per thread.
// MODE 0: init   — A rows gathered via idc from x; epilogue adds folded consts
// MODE 1: mlp1   — relu(A@B + bias)
// MODE 2: mlp2   — A@B + bias; atomic-scatter rows into x_agg by idc
// MODE 3: mp2    — [z | x_agg[idc]*inv_cnt] @ B (K=256); relu; BN-stats accum
// ---------------------------------------------------------------------------
template <int MODE>
__launch_bounds__(256)
__global__ void gemm_k(const float* __restrict__ A, const float* __restrict__ A2,
                       const float* __restrict__ B, const float* __restrict__ bias,
                       float* __restrict__ Cout, const int* __restrict__ idc,
                       const float* __restrict__ inv_cnt, float* __restrict__ x_agg,
                       const float* __restrict__ log_probs, const int* __restrict__ root_local,
                       const float* __restrict__ vl, const float* __restrict__ c0v,
                       const float* __restrict__ rev, float* __restrict__ stats) {
  constexpr int BM = 64, BN = 128, BK = 32;
  constexpr int NCH = (MODE == 3) ? 8 : 4;
  __shared__ __align__(16) float As[BK * BM];
  __shared__ __align__(16) float Bs[BK * BN];
  const int tid = threadIdx.x;
  const int row0 = blockIdx.x * BM;
  const int ty = tid >> 4, tx = tid & 15;
  const int ar = tid >> 2, ak = (tid & 3) * 8;   // A staging: row, k-offset
  const int bk = tid >> 3, bc = (tid & 7) * 4;   // B staging: k-row, col
  float acc[4][8];
#pragma unroll
  for (int i = 0; i < 4; ++i)
#pragma unroll
    for (int j = 0; j < 8; ++j) acc[i][j] = 0.f;

  for (int ch = 0; ch < NCH; ++ch) {
    {  // stage A chunk (transposed into As[k][m])
      const float* rp; float scale = 1.f; int kloc;
      const int grow = row0 + ar;
      if constexpr (MODE == 0) {
        rp = A + (size_t)idc[grow] * HH; kloc = ch * BK;
      } else if constexpr (MODE == 3) {
        if (ch < 4) { rp = A + (size_t)grow * HH; kloc = ch * BK; }
        else { int id = idc[grow]; rp = A2 + (size_t)id * HH; kloc = (ch - 4) * BK;
               scale = inv_cnt[id]; }
      } else {
        rp = A + (size_t)grow * HH; kloc = ch * BK;
      }
      float4 v0 = *(const float4*)(rp + kloc + ak);
      float4 v1 = *(const float4*)(rp + kloc + ak + 4);
      if constexpr (MODE == 3) {
        v0.x *= scale; v0.y *= scale; v0.z *= scale; v0.w *= scale;
        v1.x *= scale; v1.y *= scale; v1.z *= scale; v1.w *= scale;
      }
      As[(ak + 0) * BM + ar] = v0.x; As[(ak + 1) * BM + ar] = v0.y;
      As[(ak + 2) * BM + ar] = v0.z; As[(ak + 3) * BM + ar] = v0.w;
      As[(ak + 4) * BM + ar] = v1.x; As[(ak + 5) * BM + ar] = v1.y;
      As[(ak + 6) * BM + ar] = v1.z; As[(ak + 7) * BM + ar] = v1.w;
    }
    {  // stage B chunk
      const float* bp = B + (size_t)(ch * BK + bk) * HH;
#pragma unroll
      for (int j = 0; j < 4; ++j)
        *(float4*)&Bs[bk * BN + bc + j * 32] = *(const float4*)(bp + bc + j * 32);
    }
    __syncthreads();
#pragma unroll 4
    for (int k = 0; k < BK; ++k) {
      float4 a4  = *(const float4*)&As[k * BM + ty * 4];
      float4 b4a = *(const float4*)&Bs[k * BN + tx * 4];
      float4 b4b = *(const float4*)&Bs[k * BN + 64 + tx * 4];
      float av[4] = {a4.x, a4.y, a4.z, a4.w};
      float bv[8] = {b4a.x, b4a.y, b4a.z, b4a.w, b4b.x, b4b.y, b4b.z, b4b.w};
#pragma unroll
      for (int i = 0; i < 4; ++i)
#pragma unroll
        for (int j = 0; j < 8; ++j) acc[i][j] = fmaf(av[i], bv[j], acc[i][j]);
    }
    __syncthreads();
  }

  const int cA = tx * 4, cB = 64 + tx * 4;

  if constexpr (MODE == 0) {
    float c0a[8], vla[8], re0a[8], re1a[8];
#pragma unroll
    for (int j = 0; j < 4; ++j) {
      c0a[j] = c0v[cA + j];  c0a[4 + j] = c0v[cB + j];
      vla[j] = vl[cA + j];   vla[4 + j] = vl[cB + j];
      re0a[j] = rev[cA + j]; re0a[4 + j] = rev[cB + j];
      re1a[j] = rev[HH + cA + j]; re1a[4 + j] = rev[HH + cB + j];
    }
    const float lp = log_probs[blockIdx.x];      // BM == KSUB: block == subgraph
    const int rl = root_local[blockIdx.x];
#pragma unroll
    for (int i = 0; i < 4; ++i) {
      const int rloc = ty * 4 + i;
      const size_t r = (size_t)(row0 + rloc);
      const bool isr = (rloc == rl);
      float o[8];
#pragma unroll
      for (int j = 0; j < 8; ++j)
        o[j] = acc[i][j] + c0a[j] + lp * vla[j] + (isr ? re1a[j] : re0a[j]);
      *(float4*)&Cout[r * HH + cA] = make_float4(o[0], o[1], o[2], o[3]);
      *(float4*)&Cout[r * HH + cB] = make_float4(o[4], o[5], o[6], o[7]);
    }
  } else {
    float bb[8];
#pragma unroll
    for (int j = 0; j < 4; ++j) { bb[j] = bias[cA + j]; bb[4 + j] = bias[cB + j]; }

    if constexpr (MODE == 1) {
#pragma unroll
      for (int i = 0; i < 4; ++i) {
        const size_t r = (size_t)(row0 + ty * 4 + i);
        float o[8];
#pragma unroll
        for (int j = 0; j < 8; ++j) o[j] = fmaxf(acc[i][j] + bb[j], 0.f);
        *(float4*)&Cout[r * HH + cA] = make_float4(o[0], o[1], o[2], o[3]);
        *(float4*)&Cout[r * HH + cB] = make_float4(o[4], o[5], o[6], o[7]);
      }
    } else if constexpr (MODE == 2) {
#pragma unroll
      for (int i = 0; i < 4; ++i) {
        const size_t r = (size_t)(row0 + ty * 4 + i);
        const int id = idc[r];
        float o[8];
#pragma unroll
        for (int j = 0; j < 8; ++j) o[j] = acc[i][j] + bb[j];
        *(float4*)&Cout[r * HH + cA] = make_float4(o[0], o[1], o[2], o[3]);
        *(float4*)&Cout[r * HH + cB] = make_float4(o[4], o[5], o[6], o[7]);
        float* xa = x_agg + (size_t)id * HH;
#pragma unroll
        for (int j = 0; j < 4; ++j) {
          unsafeAtomicAdd(xa + cA + j, o[j]);
          unsafeAtomicAdd(xa + cB + j, o[4 + j]);
        }
      }
    } else {  // MODE == 3
      float psum[8], psq[8];
#pragma unroll
      for (int j = 0; j < 8; ++j) { psum[j] = 0.f; psq[j] = 0.f; }
#pragma unroll
      for (int i = 0; i < 4; ++i) {
        const size_t r = (size_t)(row0 + ty * 4 + i);
        float o[8];
#pragma unroll
        for (int j = 0; j < 8; ++j) {
          o[j] = fmaxf(acc[i][j] + bb[j], 0.f);
          psum[j] += o[j]; psq[j] += o[j] * o[j];
        }
        *(float4*)&Cout[r * HH + cA] = make_float4(o[0], o[1], o[2], o[3]);
        *(float4*)&Cout[r * HH + cB] = make_float4(o[4], o[5], o[6], o[7]);
      }
      // block-level BN stat reduction in LDS (As is dead past the last barrier)
      float* s_sum = As;
      float* s_sq  = As + HH;
      if (tid < HH) { s_sum[tid] = 0.f; s_sq[tid] = 0.f; }
      __syncthreads();
#pragma unroll
      for (int j = 0; j < 8; ++j) {
        const int c = (j < 4) ? (cA + j) : (cB + j - 4);
        unsafeAtomicAdd(&s_sum[c], psum[j]);
        unsafeAtomicAdd(&s_sq[c], psq[j]);
      }
      __syncthreads();
      if (tid < HH) {
        unsafeAtomicAdd(&stats[tid], s_sum[tid]);
        unsafeAtomicAdd(&stats[HH + tid], s_sq[tid]);
      }
    }
  }
}

// ---------------------------------------------------------------------------
// BatchNorm finalize (per channel) + fused apply with residual add
// ---------------------------------------------------------------------------
__global__ void bn_finalize_k(const float* __restrict__ stats, const float* __restrict__ gamma,
                              const float* __restrict__ beta, float* __restrict__ coef) {
  int c = threadIdx.x;
  const float invM = 1.0f / (float)SKK;
  float mu = stats[c] * invM;
  float var = fmaf(-mu, mu, stats[HH + c] * invM);
  float sc = rsqrtf(var + 1e-5f) * gamma[c];
  coef[c] = sc;
  coef[HH + c] = beta[c] - mu * sc;
}

__launch_bounds__(256)
__global__ void bn_apply_k(const float* __restrict__ u, float* __restrict__ h,
                           const float* __restrict__ coef) {
  size_t i4 = (size_t)(blockIdx.x * 256 + threadIdx.x) * 4;
  int c = (int)(i4 & 127);
  float4 uv = *(const float4*)(u + i4);
  float4 hv = *(const float4*)(h + i4);
  float4 sc = *(const float4*)(coef + c);
  float4 sh = *(const float4*)(coef + HH + c);
  float4 o;
  o.x = fmaf(uv.x, sc.x, sh.x) + hv.x;
  o.y = fmaf(uv.y, sc.y, sh.y) + hv.y;
  o.z = fmaf(uv.z, sc.z, sh.z) + hv.z;
  o.w = fmaf(uv.w, sc.w, sh.w) + hv.w;
  *(float4*)(h + i4) = o;
}

// ---------------------------------------------------------------------------
extern "C" void kernel_launch(void* const* d_in, const int* in_sizes, int n_in,
                              void* d_out, int out_size, void* d_ws, size_t ws_size,
                              hipStream_t stream) {
  const float* x          = (const float*)d_in[0];
  const float* log_probs  = (const float*)d_in[1];
  const float* node_w     = (const float*)d_in[2];
  const float* node_b     = (const float*)d_in[3];
  const float* logp_w     = (const float*)d_in[4];
  const float* logp_b     = (const float*)d_in[5];
  const float* root_emb   = (const float*)d_in[6];
  const float* init_w     = (const float*)d_in[7];
  const float* init_b     = (const float*)d_in[8];
  const float* gin_eps    = (const float*)d_in[9];
  const float* w1         = (const float*)d_in[10];
  const float* b1         = (const float*)d_in[11];
  const float* w2         = (const float*)d_in[12];
  const float* b2         = (const float*)d_in[13];
  const float* mp2w       = (const float*)d_in[14];
  const float* mp2b       = (const float*)d_in[15];
  const float* gamma      = (const float*)d_in[16];
  const float* beta       = (const float*)d_in[17];
  const int*   nodes      = (const int*)d_in[18];
  const int*   root_local = (const int*)d_in[19];
  const int*   edge_idx   = (const int*)d_in[20];
  const int*   edge_ptr   = (const int*)d_in[21];
  float* h = (float*)d_out;   // h lives in d_out across all layers

  // ---- workspace carve (~163 MB) ----
  char* wp = (char*)d_ws;
  auto take = [&](size_t bytes) { char* p = wp; wp += (bytes + 255) & ~(size_t)255; return p; };
  float* bufZ     = (float*)take((size_t)SKK * HH * 4);   // z0 / z
  float* bufT     = (float*)take((size_t)SKK * HH * 4);   // t / u
  float* x_agg    = (float*)take((size_t)NN * HH * 4);
  float* inv_cnt  = (float*)take((size_t)NN * 4);
  float* Mw       = (float*)take((size_t)HH * HH * 4);
  float* vl       = (float*)take(HH * 4);
  float* c0v      = (float*)take(HH * 4);
  float* rev      = (float*)take(2 * HH * 4);
  float* bn_stats = (float*)take(LLAY * 2 * HH * 4);
  float* bn_coef  = (float*)take(LLAY * 2 * HH * 4);
  int*   cnti     = (int*)take((size_t)NN * 4);
  int*   row_ptr  = (int*)take((size_t)(SKK + 1) * 4);
  int*   ssrc     = (int*)take((size_t)EE * 4);

  // ---- prologue (per call: ws is re-poisoned, so everything is rebuilt) ----
  hipMemsetAsync(cnti, 0, (size_t)NN * 4, stream);
  hipMemsetAsync(bn_stats, 0, LLAY * 2 * HH * 4, stream);
  fold_M_k<<<HH, HH, 0, stream>>>(node_w, init_w, Mw);
  fold_vec_k<<<1, HH, 0, stream>>>(init_w, logp_w, node_b, logp_b, init_b, root_emb,
                                   vl, c0v, rev);
  count_k<<<SKK / 256, 256, 0, stream>>>(nodes, cnti);
  invert_k<<<(NN + 255) / 256, 256, 0, stream>>>(cnti, inv_cnt);
  presort_k<<<SS, 256, 0, stream>>>(edge_idx, edge_idx + EE, edge_ptr, row_ptr, ssrc);

  // initial h
  gemm_k<0><<<SKK / 64, 256, 0, stream>>>(x, nullptr, Mw, nullptr, h, nodes, nullptr,
                                          nullptr, log_probs, root_local, vl, c0v, rev,
                                          nullptr);

  for (int l = 0; l < LLAY; ++l) {
    hipMemsetAsync(x_agg, 0, (size_t)NN * HH * 4, stream);
    gin_agg_k<<<SS, 256, 0, stream>>>(h, row_ptr, ssrc, gin_eps, l, bufZ);
    gemm_k<1><<<SKK / 64, 256, 0, stream>>>(bufZ, nullptr, w1 + (size_t)l * HH * HH,
                                            b1 + l * HH, bufT, nullptr, nullptr, nullptr,
                                            nullptr, nullptr, nullptr, nullptr, nullptr,
                                            nullptr);
    gemm_k<2><<<SKK / 64, 256, 0, stream>>>(bufT, nullptr, w2 + (size_t)l * HH * HH,
                                            b2 + l * HH, bufZ, nodes, nullptr, x_agg,
                                            nullptr, nullptr, nullptr, nullptr, nullptr,
                                            nullptr);
    gemm_k<3><<<SKK / 64, 256, 0, stream>>>(bufZ, x_agg, mp2w + (size_t)l * 2 * HH * HH,
                                            mp2b + l * HH, bufT, nodes, inv_cnt, nullptr,
                                            nullptr, nullptr, nullptr, nullptr, nullptr,
                                            bn_stats + l * 2 * HH);
    bn_finalize_k<<<1, HH, 0, stream>>>(bn_stats + l * 2 * HH, gamma + l * HH,
                                        beta + l * HH, bn_coef + l * 2 * HH);
    bn_apply_k<<<(SKK * HH / 4) / 256, 256, 0, stream>>>(bufT, h, bn_coef + l * 2 * HH);
  }
}

// Round 2
// 2060.974 us; speedup vs baseline: 1.3499x; 1.3499x over previous
//
#include <hip/hip_runtime.h>
#include <cstdint>

// Problem constants (fixed by the reference)
#define NN   50000          // global nodes
#define SS   2048           // subgraphs
#define KSUB 64             // nodes per subgraph
#define HH   128            // hidden dim (== C)
#define EE   (SS * 256)     // total edges (uniform 256/subgraph)
#define SKK  (SS * KSUB)    // 131072 flat rows
#define LLAY 5
#define NBLK 196            // ceil(NN/256) for the node scan

// ---------------------------------------------------------------------------
// Fold node_proj/logp_proj/root_emb through init_proj (exact linear algebra):
// h = gx@(Wn@Wi_a) + lp*(wl@Wi_b) + (bn@Wi_a + bl@Wi_b + bi) + root_emb[r]@Wi_c
// ---------------------------------------------------------------------------
__global__ void fold_M_k(const float* __restrict__ Wn, const float* __restrict__ Wi,
                         float* __restrict__ M) {
  int c = blockIdx.x, n = threadIdx.x;
  float s = 0.f;
  for (int k = 0; k < HH; ++k) s = fmaf(Wn[c * HH + k], Wi[k * HH + n], s);
  M[c * HH + n] = s;
}

__global__ void fold_vec_k(const float* __restrict__ Wi, const float* __restrict__ wl,
                           const float* __restrict__ bnb, const float* __restrict__ blb,
                           const float* __restrict__ bi, const float* __restrict__ remb,
                           float* __restrict__ vl, float* __restrict__ c0,
                           float* __restrict__ rev) {
  int n = threadIdx.x;
  float svl = 0.f, sc0 = bi[n], r0 = 0.f, r1 = 0.f;
  for (int k = 0; k < HH; ++k) {
    svl = fmaf(wl[k], Wi[(HH + k) * HH + n], svl);
    sc0 = fmaf(bnb[k], Wi[k * HH + n], sc0);
    sc0 = fmaf(blb[k], Wi[(HH + k) * HH + n], sc0);
    r0  = fmaf(remb[k],      Wi[(2 * HH + k) * HH + n], r0);
    r1  = fmaf(remb[HH + k], Wi[(2 * HH + k) * HH + n], r1);
  }
  vl[n] = svl; c0[n] = sc0; rev[n] = r0; rev[HH + n] = r1;
}

// ---------------------------------------------------------------------------
// Node-CSR construction: count -> exclusive scan (3 kernels) -> fill
// ---------------------------------------------------------------------------
__global__ void count_k(const int* __restrict__ idc, int* __restrict__ cnt) {
  int i = blockIdx.x * 256 + threadIdx.x;
  if (i < SKK) atomicAdd(&cnt[idc[i]], 1);
}

__global__ void scan1_k(const int* __restrict__ cnt, int* __restrict__ excl,
                        int* __restrict__ bsum) {
  __shared__ int sh[256];
  const int tid = threadIdx.x;
  const int i = blockIdx.x * 256 + tid;
  int v = (i < NN) ? cnt[i] : 0;
  sh[tid] = v;
  __syncthreads();
#pragma unroll
  for (int off = 1; off < 256; off <<= 1) {
    int t = (tid >= off) ? sh[tid - off] : 0;
    __syncthreads();
    sh[tid] += t;
    __syncthreads();
  }
  excl[i] = sh[tid] - v;
  if (tid == 255) bsum[blockIdx.x] = sh[tid];
}

__global__ void scan2_k(int* __restrict__ bsum, int* __restrict__ boff) {
  __shared__ int sh[256];
  const int tid = threadIdx.x;
  int v = (tid < NBLK) ? bsum[tid] : 0;
  sh[tid] = v;
  __syncthreads();
#pragma unroll
  for (int off = 1; off < 256; off <<= 1) {
    int t = (tid >= off) ? sh[tid - off] : 0;
    __syncthreads();
    sh[tid] += t;
    __syncthreads();
  }
  boff[tid] = sh[tid] - v;
}

__global__ void scan3_k(const int* __restrict__ excl, const int* __restrict__ boff,
                        int* __restrict__ node_ptr) {
  int i = blockIdx.x * 256 + threadIdx.x;
  if (i < NN) node_ptr[i] = excl[i] + boff[blockIdx.x];
  if (i == 0) node_ptr[NN] = SKK;
}

__global__ void fill_rows_k(const int* __restrict__ idc, const int* __restrict__ node_ptr,
                            int* __restrict__ cur, int* __restrict__ rowlist) {
  int i = blockIdx.x * 256 + threadIdx.x;
  if (i < SKK) {
    int id = idc[i];
    int pos = atomicAdd(&cur[id], 1);
    rowlist[node_ptr[id] + pos] = i;
  }
}

// ---------------------------------------------------------------------------
// Cross-subgraph scatter-mean as a GATHER: x_agg[n] = (1/cnt) * sum z[rows(n)]
// 2 nodes per 256-block; 128 threads (one channel each) per node.
// ---------------------------------------------------------------------------
__launch_bounds__(256)
__global__ void scatter_mean_k(const float* __restrict__ z, const int* __restrict__ node_ptr,
                               const int* __restrict__ rowlist, float* __restrict__ x_agg) {
  const int tid = threadIdx.x;
  const int n = blockIdx.x * 2 + (tid >> 7);
  if (n >= NN) return;
  const int c = tid & 127;
  const int p0 = node_ptr[n], p1 = node_ptr[n + 1];
  float s = 0.f;
  for (int p = p0; p < p1; ++p) s += z[(size_t)rowlist[p] * HH + c];
  const float inv = 1.0f / (float)max(p1 - p0, 1);
  x_agg[(size_t)n * HH + c] = s * inv;
}

// ---------------------------------------------------------------------------
// Per-subgraph counting sort of edges by dst -> CSR (edges are intra-subgraph)
// ---------------------------------------------------------------------------
__launch_bounds__(256)
__global__ void presort_k(const int* __restrict__ e_src, const int* __restrict__ e_dst,
                          const int* __restrict__ edge_ptr, int* __restrict__ row_ptr,
                          int* __restrict__ ssrc) {
  __shared__ int cnt[KSUB];
  __shared__ int base[KSUB];
  __shared__ int cur[KSUB];
  const int s = blockIdx.x, tid = threadIdx.x;
  const int p0 = edge_ptr[s], p1 = edge_ptr[s + 1];
  if (tid < KSUB) cnt[tid] = 0;
  __syncthreads();
  for (int e = p0 + tid; e < p1; e += 256) atomicAdd(&cnt[e_dst[e]], 1);
  __syncthreads();
  if (tid == 0) {
    int a = 0;
    for (int d = 0; d < KSUB; ++d) { base[d] = a; a += cnt[d]; }
  }
  __syncthreads();
  if (tid < KSUB) { row_ptr[s * KSUB + tid] = p0 + base[tid]; cur[tid] = base[tid]; }
  if (s == 0 && tid == 0) row_ptr[SS * KSUB] = edge_ptr[SS];
  __syncthreads();
  for (int e = p0 + tid; e < p1; e += 256) {
    int d = e_dst[e];
    int pos = atomicAdd(&cur[d], 1);
    ssrc[p0 + pos] = e_src[e];
  }
}

// ---------------------------------------------------------------------------
// GIN aggregate: z0 = (1+eps)*h + sum_{j->i} h_j   (per subgraph, in LDS)
// ---------------------------------------------------------------------------
__launch_bounds__(256)
__global__ void gin_agg_k(const float* __restrict__ h, const int* __restrict__ row_ptr,
                          const int* __restrict__ ssrc, const float* __restrict__ gin_eps,
                          const int layer, float* __restrict__ z0) {
  __shared__ __align__(16) float hl[KSUB * 132];
  const int s = blockIdx.x, tid = threadIdx.x;
  const float* hs = h + (size_t)s * KSUB * HH;
#pragma unroll
  for (int it = 0; it < 8; ++it) {
    int idx = it * 1024 + tid * 4;
    int m = idx >> 7, c = idx & 127;
    *(float4*)&hl[m * 132 + c] = *(const float4*)&hs[idx];
  }
  __syncthreads();
  const float ep1 = 1.0f + gin_eps[layer];
  const int d = tid >> 2, cg = (tid & 3) * 32;
  const int g = s * KSUB + d;
  const int e0 = row_ptr[g], e1 = row_ptr[g + 1];
  float a[32];
  const float* hp0 = &hl[d * 132 + cg];
#pragma unroll
  for (int j = 0; j < 8; ++j) {
    float4 v = *(const float4*)(hp0 + 4 * j);
    a[4 * j + 0] = ep1 * v.x; a[4 * j + 1] = ep1 * v.y;
    a[4 * j + 2] = ep1 * v.z; a[4 * j + 3] = ep1 * v.w;
  }
  for (int e = e0; e < e1; ++e) {
    const float* hp = &hl[ssrc[e] * 132 + cg];
#pragma unroll
    for (int j = 0; j < 8; ++j) {
      float4 v = *(const float4*)(hp + 4 * j);
      a[4 * j + 0] += v.x; a[4 * j + 1] += v.y;
      a[4 * j + 2] += v.z; a[4 * j + 3] += v.w;
    }
  }
  float* zp = z0 + (size_t)g * HH + cg;
#pragma unroll
  for (int j = 0; j < 8; ++j)
    *(float4*)(zp + 4 * j) = make_float4(a[4 * j], a[4 * j + 1], a[4 * j + 2], a[4 * j + 3]);
}

// ---------------------------------------------------------------------------
// Tiled fp32 GEMM, BM=64 BN=128 BK=32, 256 threads, 4x8 micro-tile per thread.
// MODE 0: init   — A rows gathered via idc from x; epilogue adds folded consts
// MODE 1: mlp1   — relu(A@B + bias)
// MODE 2: mlp2   — A@B + bias (plain)
// MODE 3: mp2    — [z | x_agg[idc]] @ B (K=256); relu; BN-stats accum
// ---------------------------------------------------------------------------
template <int MODE>
__launch_bounds__(256)
__global__ void gemm_k(const float* __restrict__ A, const float* __restrict__ A2,
                       const float* __restrict__ B, const float* __restrict__ bias,
                       float* __restrict__ Cout, const int* __restrict__ idc,
                       const float* __restrict__ log_probs, const int* __restrict__ root_local,
                       const float* __restrict__ vl, const float* __restrict__ c0v,
                       const float* __restrict__ rev, float* __restrict__ stats) {
  constexpr int BM = 64, BN = 128, BK = 32;
  constexpr int NCH = (MODE == 3) ? 8 : 4;
  __shared__ __align__(16) float As[BK * BM];
  __shared__ __align__(16) float Bs[BK * BN];
  const int tid = threadIdx.x;
  const int row0 = blockIdx.x * BM;
  const int ty = tid >> 4, tx = tid & 15;
  const int ar = tid >> 2, ak = (tid & 3) * 8;   // A staging: row, k-offset
  const int bk = tid >> 3, bc = (tid & 7) * 4;   // B staging: k-row, col
  float acc[4][8];
#pragma unroll
  for (int i = 0; i < 4; ++i)
#pragma unroll
    for (int j = 0; j < 8; ++j) acc[i][j] = 0.f;

  for (int ch = 0; ch < NCH; ++ch) {
    {  // stage A chunk (transposed into As[k][m])
      const float* rp; int kloc;
      const int grow = row0 + ar;
      if constexpr (MODE == 0) {
        rp = A + (size_t)idc[grow] * HH; kloc = ch * BK;
      } else if constexpr (MODE == 3) {
        if (ch < 4) { rp = A + (size_t)grow * HH; kloc = ch * BK; }
        else { rp = A2 + (size_t)idc[grow] * HH; kloc = (ch - 4) * BK; }
      } else {
        rp = A + (size_t)grow * HH; kloc = ch * BK;
      }
      float4 v0 = *(const float4*)(rp + kloc + ak);
      float4 v1 = *(const float4*)(rp + kloc + ak + 4);
      As[(ak + 0) * BM + ar] = v0.x; As[(ak + 1) * BM + ar] = v0.y;
      As[(ak + 2) * BM + ar] = v0.z; As[(ak + 3) * BM + ar] = v0.w;
      As[(ak + 4) * BM + ar] = v1.x; As[(ak + 5) * BM + ar] = v1.y;
      As[(ak + 6) * BM + ar] = v1.z; As[(ak + 7) * BM + ar] = v1.w;
    }
    {  // stage B chunk
      const float* bp = B + (size_t)(ch * BK + bk) * HH;
#pragma unroll
      for (int j = 0; j < 4; ++j)
        *(float4*)&Bs[bk * BN + bc + j * 32] = *(const float4*)(bp + bc + j * 32);
    }
    __syncthreads();
#pragma unroll 4
    for (int k = 0; k < BK; ++k) {
      float4 a4  = *(const float4*)&As[k * BM + ty * 4];
      float4 b4a = *(const float4*)&Bs[k * BN + tx * 4];
      float4 b4b = *(const float4*)&Bs[k * BN + 64 + tx * 4];
      float av[4] = {a4.x, a4.y, a4.z, a4.w};
      float bv[8] = {b4a.x, b4a.y, b4a.z, b4a.w, b4b.x, b4b.y, b4b.z, b4b.w};
#pragma unroll
      for (int i = 0; i < 4; ++i)
#pragma unroll
        for (int j = 0; j < 8; ++j) acc[i][j] = fmaf(av[i], bv[j], acc[i][j]);
    }
    __syncthreads();
  }

  const int cA = tx * 4, cB = 64 + tx * 4;

  if constexpr (MODE == 0) {
    float c0a[8], vla[8], re0a[8], re1a[8];
#pragma unroll
    for (int j = 0; j < 4; ++j) {
      c0a[j] = c0v[cA + j];  c0a[4 + j] = c0v[cB + j];
      vla[j] = vl[cA + j];   vla[4 + j] = vl[cB + j];
      re0a[j] = rev[cA + j]; re0a[4 + j] = rev[cB + j];
      re1a[j] = rev[HH + cA + j]; re1a[4 + j] = rev[HH + cB + j];
    }
    const float lp = log_probs[blockIdx.x];      // BM == KSUB: block == subgraph
    const int rl = root_local[blockIdx.x];
#pragma unroll
    for (int i = 0; i < 4; ++i) {
      const int rloc = ty * 4 + i;
      const size_t r = (size_t)(row0 + rloc);
      const bool isr = (rloc == rl);
      float o[8];
#pragma unroll
      for (int j = 0; j < 8; ++j)
        o[j] = acc[i][j] + c0a[j] + lp * vla[j] + (isr ? re1a[j] : re0a[j]);
      *(float4*)&Cout[r * HH + cA] = make_float4(o[0], o[1], o[2], o[3]);
      *(float4*)&Cout[r * HH + cB] = make_float4(o[4], o[5], o[6], o[7]);
    }
  } else {
    float bb[8];
#pragma unroll
    for (int j = 0; j < 4; ++j) { bb[j] = bias[cA + j]; bb[4 + j] = bias[cB + j]; }

    if constexpr (MODE == 1) {
#pragma unroll
      for (int i = 0; i < 4; ++i) {
        const size_t r = (size_t)(row0 + ty * 4 + i);
        float o[8];
#pragma unroll
        for (int j = 0; j < 8; ++j) o[j] = fmaxf(acc[i][j] + bb[j], 0.f);
        *(float4*)&Cout[r * HH + cA] = make_float4(o[0], o[1], o[2], o[3]);
        *(float4*)&Cout[r * HH + cB] = make_float4(o[4], o[5], o[6], o[7]);
      }
    } else if constexpr (MODE == 2) {
#pragma unroll
      for (int i = 0; i < 4; ++i) {
        const size_t r = (size_t)(row0 + ty * 4 + i);
        float o[8];
#pragma unroll
        for (int j = 0; j < 8; ++j) o[j] = acc[i][j] + bb[j];
        *(float4*)&Cout[r * HH + cA] = make_float4(o[0], o[1], o[2], o[3]);
        *(float4*)&Cout[r * HH + cB] = make_float4(o[4], o[5], o[6], o[7]);
      }
    } else {  // MODE == 3
      float psum[8], psq[8];
#pragma unroll
      for (int j = 0; j < 8; ++j) { psum[j] = 0.f; psq[j] = 0.f; }
#pragma unroll
      for (int i = 0; i < 4; ++i) {
        const size_t r = (size_t)(row0 + ty * 4 + i);
        float o[8];
#pragma unroll
        for (int j = 0; j < 8; ++j) {
          o[j] = fmaxf(acc[i][j] + bb[j], 0.f);
          psum[j] += o[j]; psq[j] += o[j] * o[j];
        }
        *(float4*)&Cout[r * HH + cA] = make_float4(o[0], o[1], o[2], o[3]);
        *(float4*)&Cout[r * HH + cB] = make_float4(o[4], o[5], o[6], o[7]);
      }
      // block-level BN stat reduction in LDS (As is dead past the last barrier)
      float* s_sum = As;
      float* s_sq  = As + HH;
      if (tid < HH) { s_sum[tid] = 0.f; s_sq[tid] = 0.f; }
      __syncthreads();
#pragma unroll
      for (int j = 0; j < 8; ++j) {
        const int c = (j < 4) ? (cA + j) : (cB + j - 4);
        unsafeAtomicAdd(&s_sum[c], psum[j]);
        unsafeAtomicAdd(&s_sq[c], psq[j]);
      }
      __syncthreads();
      if (tid < HH) {
        unsafeAtomicAdd(&stats[tid], s_sum[tid]);
        unsafeAtomicAdd(&stats[HH + tid], s_sq[tid]);
      }
    }
  }
}

// ---------------------------------------------------------------------------
// BatchNorm finalize (per channel) + fused apply with residual add
// ---------------------------------------------------------------------------
__global__ void bn_finalize_k(const float* __restrict__ stats, const float* __restrict__ gamma,
                              const float* __restrict__ beta, float* __restrict__ coef) {
  int c = threadIdx.x;
  const float invM = 1.0f / (float)SKK;
  float mu = stats[c] * invM;
  float var = fmaf(-mu, mu, stats[HH + c] * invM);
  float sc = rsqrtf(var + 1e-5f) * gamma[c];
  coef[c] = sc;
  coef[HH + c] = beta[c] - mu * sc;
}

__launch_bounds__(256)
__global__ void bn_apply_k(const float* __restrict__ u, float* __restrict__ h,
                           const float* __restrict__ coef) {
  size_t i4 = (size_t)(blockIdx.x * 256 + threadIdx.x) * 4;
  int c = (int)(i4 & 127);
  float4 uv = *(const float4*)(u + i4);
  float4 hv = *(const float4*)(h + i4);
  float4 sc = *(const float4*)(coef + c);
  float4 sh = *(const float4*)(coef + HH + c);
  float4 o;
  o.x = fmaf(uv.x, sc.x, sh.x) + hv.x;
  o.y = fmaf(uv.y, sc.y, sh.y) + hv.y;
  o.z = fmaf(uv.z, sc.z, sh.z) + hv.z;
  o.w = fmaf(uv.w, sc.w, sh.w) + hv.w;
  *(float4*)(h + i4) = o;
}

// ---------------------------------------------------------------------------
extern "C" void kernel_launch(void* const* d_in, const int* in_sizes, int n_in,
                              void* d_out, int out_size, void* d_ws, size_t ws_size,
                              hipStream_t stream) {
  const float* x          = (const float*)d_in[0];
  const float* log_probs  = (const float*)d_in[1];
  const float* node_w     = (const float*)d_in[2];
  const float* node_b     = (const float*)d_in[3];
  const float* logp_w     = (const float*)d_in[4];
  const float* logp_b     = (const float*)d_in[5];
  const float* root_emb   = (const float*)d_in[6];
  const float* init_w     = (const float*)d_in[7];
  const float* init_b     = (const float*)d_in[8];
  const float* gin_eps    = (const float*)d_in[9];
  const float* w1         = (const float*)d_in[10];
  const float* b1         = (const float*)d_in[11];
  const float* w2         = (const float*)d_in[12];
  const float* b2         = (const float*)d_in[13];
  const float* mp2w       = (const float*)d_in[14];
  const float* mp2b       = (const float*)d_in[15];
  const float* gamma      = (const float*)d_in[16];
  const float* beta       = (const float*)d_in[17];
  const int*   nodes      = (const int*)d_in[18];
  const int*   root_local = (const int*)d_in[19];
  const int*   edge_idx   = (const int*)d_in[20];
  const int*   edge_ptr   = (const int*)d_in[21];
  float* h = (float*)d_out;   // h lives in d_out across all layers

  // ---- workspace carve ----
  char* wp = (char*)d_ws;
  auto take = [&](size_t bytes) { char* p = wp; wp += (bytes + 255) & ~(size_t)255; return p; };
  float* bufZ     = (float*)take((size_t)SKK * HH * 4);   // z0 / z
  float* bufT     = (float*)take((size_t)SKK * HH * 4);   // t / u
  float* x_agg    = (float*)take((size_t)NN * HH * 4);
  float* Mw       = (float*)take((size_t)HH * HH * 4);
  float* vl       = (float*)take(HH * 4);
  float* c0v      = (float*)take(HH * 4);
  float* rev      = (float*)take(2 * HH * 4);
  float* bn_stats = (float*)take(LLAY * 2 * HH * 4);
  float* bn_coef  = (float*)take(LLAY * 2 * HH * 4);
  int*   cnti     = (int*)take((size_t)NN * 4);
  int*   excl     = (int*)take((size_t)NBLK * 256 * 4);
  int*   bsum     = (int*)take(256 * 4);
  int*   boff     = (int*)take(256 * 4);
  int*   node_ptr = (int*)take((size_t)(NN + 1) * 4);
  int*   cur      = (int*)take((size_t)NN * 4);
  int*   rowlist  = (int*)take((size_t)SKK * 4);
  int*   row_ptr  = (int*)take((size_t)(SKK + 1) * 4);
  int*   ssrc     = (int*)take((size_t)EE * 4);

  // ---- prologue (per call: ws is re-poisoned, so everything is rebuilt) ----
  hipMemsetAsync(cnti, 0, (size_t)NN * 4, stream);
  hipMemsetAsync(cur, 0, (size_t)NN * 4, stream);
  hipMemsetAsync(bn_stats, 0, LLAY * 2 * HH * 4, stream);
  fold_M_k<<<HH, HH, 0, stream>>>(node_w, init_w, Mw);
  fold_vec_k<<<1, HH, 0, stream>>>(init_w, logp_w, node_b, logp_b, init_b, root_emb,
                                   vl, c0v, rev);
  count_k<<<SKK / 256, 256, 0, stream>>>(nodes, cnti);
  scan1_k<<<NBLK, 256, 0, stream>>>(cnti, excl, bsum);
  scan2_k<<<1, 256, 0, stream>>>(bsum, boff);
  scan3_k<<<NBLK, 256, 0, stream>>>(excl, boff, node_ptr);
  fill_rows_k<<<SKK / 256, 256, 0, stream>>>(nodes, node_ptr, cur, rowlist);
  presort_k<<<SS, 256, 0, stream>>>(edge_idx, edge_idx + EE, edge_ptr, row_ptr, ssrc);

  // initial h
  gemm_k<0><<<SKK / 64, 256, 0, stream>>>(x, nullptr, Mw, nullptr, h, nodes,
                                          log_probs, root_local, vl, c0v, rev, nullptr);

  for (int l = 0; l < LLAY; ++l) {
    gin_agg_k<<<SS, 256, 0, stream>>>(h, row_ptr, ssrc, gin_eps, l, bufZ);
    gemm_k<1><<<SKK / 64, 256, 0, stream>>>(bufZ, nullptr, w1 + (size_t)l * HH * HH,
                                            b1 + l * HH, bufT, nullptr, nullptr, nullptr,
                                            nullptr, nullptr, nullptr, nullptr);
    gemm_k<2><<<SKK / 64, 256, 0, stream>>>(bufT, nullptr, w2 + (size_t)l * HH * HH,
                                            b2 + l * HH, bufZ, nullptr, nullptr, nullptr,
                                            nullptr, nullptr, nullptr, nullptr);
    scatter_mean_k<<<NN / 2, 256, 0, stream>>>(bufZ, node_ptr, rowlist, x_agg);
    gemm_k<3><<<SKK / 64, 256, 0, stream>>>(bufZ, x_agg, mp2w + (size_t)l * 2 * HH * HH,
                                            mp2b + l * HH, bufT, nodes, nullptr, nullptr,
                                            nullptr, nullptr, nullptr,
                                            bn_stats + l * 2 * HH);
    bn_finalize_k<<<1, HH, 0, stream>>>(bn_stats + l * 2 * HH, gamma + l * HH,
                                        beta + l * HH, bn_coef + l * 2 * HH);
    bn_apply_k<<<(SKK * HH / 4) / 256, 256, 0, stream>>>(bufT, h, bn_coef + l * 2 * HH);
  }
}

// Round 4
// 1294.665 us; speedup vs baseline: 2.1489x; 1.5919x over previous
//
#include <hip/hip_runtime.h>
#include <cstdint>

#define NN   50000
#define SS   2048
#define KSUB 64
#define HH   128
#define EE   (SS * 256)
#define SKK  (SS * KSUB)    // 131072
#define LLAY 5
#define NBLK 196            // ceil(NN/256)

typedef __attribute__((ext_vector_type(8))) short bhalf8;
typedef __attribute__((ext_vector_type(4))) float f32x4;

__device__ __forceinline__ ushort f2b(float f) {
  uint u = __builtin_bit_cast(uint, f);
  uint r = (u + 0x7FFFu + ((u >> 16) & 1u)) >> 16;
  return (ushort)r;
}
__device__ __forceinline__ float b2f(ushort u) {
  uint v = ((uint)u) << 16;
  return __builtin_bit_cast(float, v);
}
// split fp32 -> (hi, lo) bf16 pair; hi + lo ~= f with ~2^-18 residual
__device__ __forceinline__ void fsplit(float f, ushort& hi, ushort& lo) {
  hi = f2b(f);
  lo = f2b(f - b2f(hi));
}

// ---------------------------------------------------------------------------
// Fold node_proj through init_proj; emit split bf16 B^T layout [n][c]
// ---------------------------------------------------------------------------
__global__ void fold_M_k(const float* __restrict__ Wn, const float* __restrict__ Wi,
                         ushort* __restrict__ Mth, ushort* __restrict__ Mtl) {
  int c = blockIdx.x, n = threadIdx.x;
  float s = 0.f;
  for (int k = 0; k < HH; ++k) s = fmaf(Wn[c * HH + k], Wi[k * HH + n], s);
  ushort hi, lo; fsplit(s, hi, lo);
  Mth[n * HH + c] = hi; Mtl[n * HH + c] = lo;
}

__global__ void fold_vec_k(const float* __restrict__ Wi, const float* __restrict__ wl,
                           const float* __restrict__ bnb, const float* __restrict__ blb,
                           const float* __restrict__ bi, const float* __restrict__ remb,
                           float* __restrict__ vl, float* __restrict__ c0,
                           float* __restrict__ rev) {
  int n = threadIdx.x;
  float svl = 0.f, sc0 = bi[n], r0 = 0.f, r1 = 0.f;
  for (int k = 0; k < HH; ++k) {
    svl = fmaf(wl[k], Wi[(HH + k) * HH + n], svl);
    sc0 = fmaf(bnb[k], Wi[k * HH + n], sc0);
    sc0 = fmaf(blb[k], Wi[(HH + k) * HH + n], sc0);
    r0  = fmaf(remb[k],      Wi[(2 * HH + k) * HH + n], r0);
    r1  = fmaf(remb[HH + k], Wi[(2 * HH + k) * HH + n], r1);
  }
  vl[n] = svl; c0[n] = sc0; rev[n] = r0; rev[HH + n] = r1;
}

// ---------------------------------------------------------------------------
// Transpose+convert all layer weights to split bf16 B^T layout (one launch).
// ---------------------------------------------------------------------------
__global__ void wconv_k(const float* __restrict__ w1, const float* __restrict__ w2,
                        const float* __restrict__ mp2w,
                        ushort* __restrict__ w1th, ushort* __restrict__ w1tl,
                        ushort* __restrict__ w2th, ushort* __restrict__ w2tl,
                        ushort* __restrict__ mp2th, ushort* __restrict__ mp2tl) {
  int b = blockIdx.x, n = threadIdx.x;
  ushort hi, lo;
  if (b < 640) {
    int l = b >> 7, k = b & 127;
    fsplit(w1[((size_t)l * HH + k) * HH + n], hi, lo);
    w1th[((size_t)l * HH + n) * HH + k] = hi;
    w1tl[((size_t)l * HH + n) * HH + k] = lo;
  } else if (b < 1280) {
    int bb = b - 640; int l = bb >> 7, k = bb & 127;
    fsplit(w2[((size_t)l * HH + k) * HH + n], hi, lo);
    w2th[((size_t)l * HH + n) * HH + k] = hi;
    w2tl[((size_t)l * HH + n) * HH + k] = lo;
  } else {
    int bb = b - 1280; int l = bb >> 8, k = bb & 255;
    fsplit(mp2w[((size_t)l * 256 + k) * HH + n], hi, lo);
    mp2th[((size_t)l * HH + n) * 256 + k] = hi;
    mp2tl[((size_t)l * HH + n) * 256 + k] = lo;
  }
}

// ---------------------------------------------------------------------------
// Node-CSR construction: count -> exclusive scan -> fill
// ---------------------------------------------------------------------------
__global__ void count_k(const int* __restrict__ idc, int* __restrict__ cnt) {
  int i = blockIdx.x * 256 + threadIdx.x;
  if (i < SKK) atomicAdd(&cnt[idc[i]], 1);
}

__global__ void scan1_k(const int* __restrict__ cnt, int* __restrict__ excl,
                        int* __restrict__ bsum) {
  __shared__ int sh[256];
  const int tid = threadIdx.x;
  const int i = blockIdx.x * 256 + tid;
  int v = (i < NN) ? cnt[i] : 0;
  sh[tid] = v;
  __syncthreads();
#pragma unroll
  for (int off = 1; off < 256; off <<= 1) {
    int t = (tid >= off) ? sh[tid - off] : 0;
    __syncthreads();
    sh[tid] += t;
    __syncthreads();
  }
  excl[i] = sh[tid] - v;
  if (tid == 255) bsum[blockIdx.x] = sh[tid];
}

__global__ void scan2_k(int* __restrict__ bsum, int* __restrict__ boff) {
  __shared__ int sh[256];
  const int tid = threadIdx.x;
  int v = (tid < NBLK) ? bsum[tid] : 0;
  sh[tid] = v;
  __syncthreads();
#pragma unroll
  for (int off = 1; off < 256; off <<= 1) {
    int t = (tid >= off) ? sh[tid - off] : 0;
    __syncthreads();
    sh[tid] += t;
    __syncthreads();
  }
  boff[tid] = sh[tid] - v;
}

__global__ void scan3_k(const int* __restrict__ excl, const int* __restrict__ boff,
                        int* __restrict__ node_ptr) {
  int i = blockIdx.x * 256 + threadIdx.x;
  if (i < NN) node_ptr[i] = excl[i] + boff[blockIdx.x];
  if (i == 0) node_ptr[NN] = SKK;
}

__global__ void fill_rows_k(const int* __restrict__ idc, const int* __restrict__ node_ptr,
                            int* __restrict__ cur, int* __restrict__ rowlist) {
  int i = blockIdx.x * 256 + threadIdx.x;
  if (i < SKK) {
    int id = idc[i];
    int pos = atomicAdd(&cur[id], 1);
    rowlist[node_ptr[id] + pos] = i;
  }
}

// ---------------------------------------------------------------------------
// Cross-subgraph scatter-mean as a GATHER (split in, fp32 acc, split out)
// ---------------------------------------------------------------------------
__launch_bounds__(256)
__global__ void scatter_mean_k(const ushort* __restrict__ zh, const ushort* __restrict__ zl,
                               const int* __restrict__ node_ptr,
                               const int* __restrict__ rowlist,
                               ushort* __restrict__ xah, ushort* __restrict__ xal) {
  const int tid = threadIdx.x;
  const int n = blockIdx.x * 2 + (tid >> 7);
  if (n >= NN) return;
  const int c = tid & 127;
  const int p0 = node_ptr[n], p1 = node_ptr[n + 1];
  float s = 0.f;
  for (int p = p0; p < p1; ++p) {
    const size_t off = (size_t)rowlist[p] * HH + c;
    s += b2f(zh[off]) + b2f(zl[off]);
  }
  const float inv = 1.0f / (float)max(p1 - p0, 1);
  ushort hi, lo; fsplit(s * inv, hi, lo);
  xah[(size_t)n * HH + c] = hi;
  xal[(size_t)n * HH + c] = lo;
}

// ---------------------------------------------------------------------------
// Per-subgraph counting sort of edges by dst -> CSR
// ---------------------------------------------------------------------------
__launch_bounds__(256)
__global__ void presort_k(const int* __restrict__ e_src, const int* __restrict__ e_dst,
                          const int* __restrict__ edge_ptr, int* __restrict__ row_ptr,
                          int* __restrict__ ssrc) {
  __shared__ int cnt[KSUB];
  __shared__ int base[KSUB];
  __shared__ int cur[KSUB];
  const int s = blockIdx.x, tid = threadIdx.x;
  const int p0 = edge_ptr[s], p1 = edge_ptr[s + 1];
  if (tid < KSUB) cnt[tid] = 0;
  __syncthreads();
  for (int e = p0 + tid; e < p1; e += 256) atomicAdd(&cnt[e_dst[e]], 1);
  __syncthreads();
  if (tid == 0) {
    int a = 0;
    for (int d = 0; d < KSUB; ++d) { base[d] = a; a += cnt[d]; }
  }
  __syncthreads();
  if (tid < KSUB) { row_ptr[s * KSUB + tid] = p0 + base[tid]; cur[tid] = base[tid]; }
  if (s == 0 && tid == 0) row_ptr[SS * KSUB] = edge_ptr[SS];
  __syncthreads();
  for (int e = p0 + tid; e < p1; e += 256) {
    int d = e_dst[e];
    int pos = atomicAdd(&cur[d], 1);
    ssrc[p0 + pos] = e_src[e];
  }
}

// ---------------------------------------------------------------------------
// GIN aggregate: fp32 h in, split bf16 z out. fp32 LDS tile, stride 132.
// ---------------------------------------------------------------------------
__launch_bounds__(256)
__global__ void gin_agg_k(const float* __restrict__ h, const int* __restrict__ row_ptr,
                          const int* __restrict__ ssrc, const float* __restrict__ gin_eps,
                          const int layer, ushort* __restrict__ zh,
                          ushort* __restrict__ zl) {
  __shared__ __align__(16) float hl[KSUB * 132];
  const int s = blockIdx.x, tid = threadIdx.x;
  const float* hs = h + (size_t)s * KSUB * HH;
#pragma unroll
  for (int it = 0; it < 8; ++it) {
    int idx = it * 1024 + tid * 4;
    int m = idx >> 7, c = idx & 127;
    *(float4*)&hl[m * 132 + c] = *(const float4*)&hs[idx];
  }
  __syncthreads();
  const float ep1 = 1.0f + gin_eps[layer];
  const int d = tid >> 2, cg = (tid & 3) * 32;
  const int g = s * KSUB + d;
  const int e0 = row_ptr[g], e1 = row_ptr[g + 1];
  float a[32];
  const float* hp0 = &hl[d * 132 + cg];
#pragma unroll
  for (int j = 0; j < 8; ++j) {
    float4 v = *(const float4*)(hp0 + 4 * j);
    a[4 * j + 0] = ep1 * v.x; a[4 * j + 1] = ep1 * v.y;
    a[4 * j + 2] = ep1 * v.z; a[4 * j + 3] = ep1 * v.w;
  }
  for (int e = e0; e < e1; ++e) {
    const float* hp = &hl[ssrc[e] * 132 + cg];
#pragma unroll
    for (int j = 0; j < 8; ++j) {
      float4 v = *(const float4*)(hp + 4 * j);
      a[4 * j + 0] += v.x; a[4 * j + 1] += v.y;
      a[4 * j + 2] += v.z; a[4 * j + 3] += v.w;
    }
  }
  const size_t zo = (size_t)g * HH + cg;
#pragma unroll
  for (int q = 0; q < 4; ++q) {
    ushort th[8], tl[8];
#pragma unroll
    for (int e = 0; e < 8; ++e) fsplit(a[q * 8 + e], th[e], tl[e]);
    *(uint4*)&zh[zo + q * 8] = *(uint4*)th;
    *(uint4*)&zl[zo + q * 8] = *(uint4*)tl;
  }
}

// ---------------------------------------------------------------------------
// Split-bf16 MFMA GEMM (bf16x3: Ah*Bh + Al*Bh + Ah*Bl, fp32 acc ~ fp32 GEMM).
// 128x128 block tile, 4 waves, each wave 4x4 accs of 16x16x32. BK=32 chunks.
// LDS rows padded to 40 shorts (80 B stride, 16B-aligned fragments).
// MODE 0: init — A = fp32 x rows gathered via idc, split in staging; -> h fp32
// MODE 1: mlp1 — relu(A@B+b) -> split
// MODE 2: mlp2 — A@B+b -> split
// MODE 3: mp2  — [z | x_agg[idc]] (K=256); relu; BN stats; -> u fp32
// ---------------------------------------------------------------------------
template <int MODE>
__launch_bounds__(256, 2)
__global__ void mgemm_k(const ushort* __restrict__ Ah, const ushort* __restrict__ Al,
                        const ushort* __restrict__ A2h, const ushort* __restrict__ A2l,
                        const float* __restrict__ Afp,
                        const ushort* __restrict__ Bh, const ushort* __restrict__ Bl,
                        const float* __restrict__ bias,
                        ushort* __restrict__ Ch, ushort* __restrict__ Cl,
                        float* __restrict__ Cf,
                        const int* __restrict__ idc, const float* __restrict__ log_probs,
                        const int* __restrict__ root_local, const float* __restrict__ vl,
                        const float* __restrict__ c0v, const float* __restrict__ rev,
                        float* __restrict__ stats) {
  constexpr int NCH = (MODE == 3) ? 8 : 4;
  constexpr int KTOT = (MODE == 3) ? 256 : 128;
  constexpr int LDP = 40;   // LDS row stride in shorts
  __shared__ __align__(16) ushort Ash[128 * LDP];
  __shared__ __align__(16) ushort Asl[128 * LDP];
  __shared__ __align__(16) ushort Bsh[128 * LDP];
  __shared__ __align__(16) ushort Bsl[128 * LDP];
  const int tid = threadIdx.x;
  const int row0 = blockIdx.x * 128;
  const int lane = tid & 63, wv = tid >> 6;
  const int wm = (wv >> 1) * 64, wn = (wv & 1) * 64;
  const int fr = lane & 15, quad = lane >> 4;
  const int sr = tid >> 1;            // staging row 0..127
  const int sc = (tid & 1) * 16;      // staging short-offset {0,16}

  f32x4 acc[4][4];
#pragma unroll
  for (int i = 0; i < 4; ++i)
#pragma unroll
    for (int j = 0; j < 4; ++j) acc[i][j] = (f32x4){0.f, 0.f, 0.f, 0.f};

  for (int ch = 0; ch < NCH; ++ch) {
    // ---- stage A chunk ----
    if constexpr (MODE == 0) {
      const float* src = Afp + (size_t)idc[row0 + sr] * HH + ch * 32 + sc;
      float fv[16];
      *(float4*)&fv[0]  = *(const float4*)(src);
      *(float4*)&fv[4]  = *(const float4*)(src + 4);
      *(float4*)&fv[8]  = *(const float4*)(src + 8);
      *(float4*)&fv[12] = *(const float4*)(src + 12);
      ushort hi[16], lo[16];
#pragma unroll
      for (int e = 0; e < 16; ++e) fsplit(fv[e], hi[e], lo[e]);
      *(uint4*)&Ash[sr * LDP + sc]     = *(uint4*)&hi[0];
      *(uint4*)&Ash[sr * LDP + sc + 8] = *(uint4*)&hi[8];
      *(uint4*)&Asl[sr * LDP + sc]     = *(uint4*)&lo[0];
      *(uint4*)&Asl[sr * LDP + sc + 8] = *(uint4*)&lo[8];
    } else {
      const ushort *sh_, *sl_;
      if (MODE == 3 && ch >= 4) {
        const size_t off = (size_t)idc[row0 + sr] * HH + (ch - 4) * 32 + sc;
        sh_ = A2h + off; sl_ = A2l + off;
      } else {
        const size_t off = (size_t)(row0 + sr) * HH + ch * 32 + sc;
        sh_ = Ah + off; sl_ = Al + off;
      }
      *(uint4*)&Ash[sr * LDP + sc]     = *(const uint4*)(sh_);
      *(uint4*)&Ash[sr * LDP + sc + 8] = *(const uint4*)(sh_ + 8);
      *(uint4*)&Asl[sr * LDP + sc]     = *(const uint4*)(sl_);
      *(uint4*)&Asl[sr * LDP + sc + 8] = *(const uint4*)(sl_ + 8);
    }
    // ---- stage B chunk (Bt layout [n][KTOT]) ----
    {
      const size_t off = (size_t)sr * KTOT + ch * 32 + sc;
      *(uint4*)&Bsh[sr * LDP + sc]     = *(const uint4*)(Bh + off);
      *(uint4*)&Bsh[sr * LDP + sc + 8] = *(const uint4*)(Bh + off + 8);
      *(uint4*)&Bsl[sr * LDP + sc]     = *(const uint4*)(Bl + off);
      *(uint4*)&Bsl[sr * LDP + sc + 8] = *(const uint4*)(Bl + off + 8);
    }
    __syncthreads();
    // ---- one K=32 MFMA step, bf16x3 ----
    bhalf8 afh[4], afl[4], bfh[4], bfl[4];
#pragma unroll
    for (int i = 0; i < 4; ++i) {
      const int r = (wm + i * 16 + fr) * LDP + quad * 8;
      afh[i] = *(const bhalf8*)&Ash[r];
      afl[i] = *(const bhalf8*)&Asl[r];
    }
#pragma unroll
    for (int j = 0; j < 4; ++j) {
      const int r = (wn + j * 16 + fr) * LDP + quad * 8;
      bfh[j] = *(const bhalf8*)&Bsh[r];
      bfl[j] = *(const bhalf8*)&Bsl[r];
    }
#pragma unroll
    for (int i = 0; i < 4; ++i)
#pragma unroll
      for (int j = 0; j < 4; ++j) {
        acc[i][j] = __builtin_amdgcn_mfma_f32_16x16x32_bf16(afh[i], bfh[j], acc[i][j], 0, 0, 0);
        acc[i][j] = __builtin_amdgcn_mfma_f32_16x16x32_bf16(afl[i], bfh[j], acc[i][j], 0, 0, 0);
        acc[i][j] = __builtin_amdgcn_mfma_f32_16x16x32_bf16(afh[i], bfl[j], acc[i][j], 0, 0, 0);
      }
    __syncthreads();
  }

  // ---- epilogue ----
  const int nj[4] = {wn + fr, wn + 16 + fr, wn + 32 + fr, wn + 48 + fr};

  if constexpr (MODE == 0) {
    float c0a[4], vla[4], re0[4], re1[4];
#pragma unroll
    for (int j = 0; j < 4; ++j) {
      c0a[j] = c0v[nj[j]]; vla[j] = vl[nj[j]];
      re0[j] = rev[nj[j]]; re1[j] = rev[HH + nj[j]];
    }
#pragma unroll
    for (int i = 0; i < 4; ++i)
#pragma unroll
      for (int r = 0; r < 4; ++r) {
        const int m = row0 + wm + i * 16 + quad * 4 + r;
        const int s = m >> 6;
        const float lp = log_probs[s];
        const bool isr = (m & 63) == root_local[s];
        const size_t base = (size_t)m * HH;
#pragma unroll
        for (int j = 0; j < 4; ++j)
          Cf[base + nj[j]] = acc[i][j][r] + c0a[j] + lp * vla[j] + (isr ? re1[j] : re0[j]);
      }
  } else {
    float bb[4];
#pragma unroll
    for (int j = 0; j < 4; ++j) bb[j] = bias[nj[j]];
    float psum[4] = {0.f, 0.f, 0.f, 0.f}, psq[4] = {0.f, 0.f, 0.f, 0.f};
#pragma unroll
    for (int i = 0; i < 4; ++i)
#pragma unroll
      for (int r = 0; r < 4; ++r) {
        const int m = row0 + wm + i * 16 + quad * 4 + r;
        const size_t base = (size_t)m * HH;
#pragma unroll
        for (int j = 0; j < 4; ++j) {
          float o = acc[i][j][r] + bb[j];
          if constexpr (MODE != 2) o = fmaxf(o, 0.f);
          if constexpr (MODE == 3) {
            Cf[base + nj[j]] = o;
            psum[j] += o; psq[j] += o * o;
          } else {
            ushort hi, lo; fsplit(o, hi, lo);
            Ch[base + nj[j]] = hi;
            Cl[base + nj[j]] = lo;
          }
        }
      }
    if constexpr (MODE == 3) {
      float* ssum = (float*)Ash;      // dead past last barrier
      float* ssq = ssum + HH;
      if (tid < HH) { ssum[tid] = 0.f; ssq[tid] = 0.f; }
      __syncthreads();
#pragma unroll
      for (int j = 0; j < 4; ++j) {
        atomicAdd(&ssum[nj[j]], psum[j]);
        atomicAdd(&ssq[nj[j]], psq[j]);
      }
      __syncthreads();
      if (tid < HH) {
        unsafeAtomicAdd(&stats[tid], ssum[tid]);
        unsafeAtomicAdd(&stats[HH + tid], ssq[tid]);
      }
    }
  }
}

// ---------------------------------------------------------------------------
// BatchNorm finalize + fused apply with residual (all fp32)
// ---------------------------------------------------------------------------
__global__ void bn_finalize_k(const float* __restrict__ stats, const float* __restrict__ gamma,
                              const float* __restrict__ beta, float* __restrict__ coef) {
  int c = threadIdx.x;
  const float invM = 1.0f / (float)SKK;
  float mu = stats[c] * invM;
  float var = fmaf(-mu, mu, stats[HH + c] * invM);
  float sc = rsqrtf(var + 1e-5f) * gamma[c];
  coef[c] = sc;
  coef[HH + c] = beta[c] - mu * sc;
}

__launch_bounds__(256)
__global__ void bn_apply_k(const float* __restrict__ u, float* __restrict__ h,
                           const float* __restrict__ coef) {
  size_t i4 = (size_t)(blockIdx.x * 256 + threadIdx.x) * 4;
  int c = (int)(i4 & 127);
  float4 uv = *(const float4*)(u + i4);
  float4 hv = *(const float4*)(h + i4);
  float4 sc = *(const float4*)(coef + c);
  float4 sh = *(const float4*)(coef + HH + c);
  float4 o;
  o.x = fmaf(uv.x, sc.x, sh.x) + hv.x;
  o.y = fmaf(uv.y, sc.y, sh.y) + hv.y;
  o.z = fmaf(uv.z, sc.z, sh.z) + hv.z;
  o.w = fmaf(uv.w, sc.w, sh.w) + hv.w;
  *(float4*)(h + i4) = o;
}

// ---------------------------------------------------------------------------
extern "C" void kernel_launch(void* const* d_in, const int* in_sizes, int n_in,
                              void* d_out, int out_size, void* d_ws, size_t ws_size,
                              hipStream_t stream) {
  const float* x          = (const float*)d_in[0];
  const float* log_probs  = (const float*)d_in[1];
  const float* node_w     = (const float*)d_in[2];
  const float* node_b     = (const float*)d_in[3];
  const float* logp_w     = (const float*)d_in[4];
  const float* logp_b     = (const float*)d_in[5];
  const float* root_emb   = (const float*)d_in[6];
  const float* init_w     = (const float*)d_in[7];
  const float* init_b     = (const float*)d_in[8];
  const float* gin_eps    = (const float*)d_in[9];
  const float* w1         = (const float*)d_in[10];
  const float* b1         = (const float*)d_in[11];
  const float* w2         = (const float*)d_in[12];
  const float* b2         = (const float*)d_in[13];
  const float* mp2w       = (const float*)d_in[14];
  const float* mp2b       = (const float*)d_in[15];
  const float* gamma      = (const float*)d_in[16];
  const float* beta       = (const float*)d_in[17];
  const int*   nodes      = (const int*)d_in[18];
  const int*   root_local = (const int*)d_in[19];
  const int*   edge_idx   = (const int*)d_in[20];
  const int*   edge_ptr   = (const int*)d_in[21];
  float* h = (float*)d_out;   // fp32 residual stream lives in d_out

  // ---- workspace carve (~160 MB) ----
  char* wp = (char*)d_ws;
  auto take = [&](size_t bytes) { char* p = wp; wp += (bytes + 255) & ~(size_t)255; return p; };
  ushort* zh    = (ushort*)take((size_t)SKK * HH * 2);   // 32 MB
  ushort* zl    = (ushort*)take((size_t)SKK * HH * 2);
  ushort* th    = (ushort*)take((size_t)SKK * HH * 2);
  ushort* tl    = (ushort*)take((size_t)SKK * HH * 2);
  float*  uf    = (float*)th;                            // overlays th+tl (64 MB)
  ushort* xah   = (ushort*)take((size_t)NN * HH * 2);
  ushort* xal   = (ushort*)take((size_t)NN * HH * 2);
  ushort* Mth   = (ushort*)take((size_t)HH * HH * 2);
  ushort* Mtl   = (ushort*)take((size_t)HH * HH * 2);
  ushort* w1th  = (ushort*)take((size_t)LLAY * HH * HH * 2);
  ushort* w1tl  = (ushort*)take((size_t)LLAY * HH * HH * 2);
  ushort* w2th  = (ushort*)take((size_t)LLAY * HH * HH * 2);
  ushort* w2tl  = (ushort*)take((size_t)LLAY * HH * HH * 2);
  ushort* mp2th = (ushort*)take((size_t)LLAY * HH * 256 * 2);
  ushort* mp2tl = (ushort*)take((size_t)LLAY * HH * 256 * 2);
  float* vl       = (float*)take(HH * 4);
  float* c0v      = (float*)take(HH * 4);
  float* rev      = (float*)take(2 * HH * 4);
  float* bn_stats = (float*)take(LLAY * 2 * HH * 4);
  float* bn_coef  = (float*)take(LLAY * 2 * HH * 4);
  int*   cnti     = (int*)take((size_t)NN * 4);
  int*   excl     = (int*)take((size_t)NBLK * 256 * 4);
  int*   bsum     = (int*)take(256 * 4);
  int*   boff     = (int*)take(256 * 4);
  int*   node_ptr = (int*)take((size_t)(NN + 1) * 4);
  int*   cur      = (int*)take((size_t)NN * 4);
  int*   rowlist  = (int*)take((size_t)SKK * 4);
  int*   row_ptr  = (int*)take((size_t)(SKK + 1) * 4);
  int*   ssrc     = (int*)take((size_t)EE * 4);

  // ---- prologue ----
  hipMemsetAsync(cnti, 0, (size_t)NN * 4, stream);
  hipMemsetAsync(cur, 0, (size_t)NN * 4, stream);
  hipMemsetAsync(bn_stats, 0, LLAY * 2 * HH * 4, stream);
  fold_M_k<<<HH, HH, 0, stream>>>(node_w, init_w, Mth, Mtl);
  fold_vec_k<<<1, HH, 0, stream>>>(init_w, logp_w, node_b, logp_b, init_b, root_emb,
                                   vl, c0v, rev);
  wconv_k<<<2560, HH, 0, stream>>>(w1, w2, mp2w, w1th, w1tl, w2th, w2tl, mp2th, mp2tl);
  count_k<<<SKK / 256, 256, 0, stream>>>(nodes, cnti);
  scan1_k<<<NBLK, 256, 0, stream>>>(cnti, excl, bsum);
  scan2_k<<<1, 256, 0, stream>>>(bsum, boff);
  scan3_k<<<NBLK, 256, 0, stream>>>(excl, boff, node_ptr);
  fill_rows_k<<<SKK / 256, 256, 0, stream>>>(nodes, node_ptr, cur, rowlist);
  presort_k<<<SS, 256, 0, stream>>>(edge_idx, edge_idx + EE, edge_ptr, row_ptr, ssrc);

  // initial h (fp32, in d_out)
  mgemm_k<0><<<SKK / 128, 256, 0, stream>>>(nullptr, nullptr, nullptr, nullptr, x,
                                            Mth, Mtl, nullptr, nullptr, nullptr, h,
                                            nodes, log_probs, root_local, vl, c0v, rev,
                                            nullptr);

  for (int l = 0; l < LLAY; ++l) {
    gin_agg_k<<<SS, 256, 0, stream>>>(h, row_ptr, ssrc, gin_eps, l, zh, zl);
    mgemm_k<1><<<SKK / 128, 256, 0, stream>>>(zh, zl, nullptr, nullptr, nullptr,
                                              w1th + (size_t)l * HH * HH,
                                              w1tl + (size_t)l * HH * HH,
                                              b1 + l * HH, th, tl, nullptr,
                                              nullptr, nullptr, nullptr, nullptr,
                                              nullptr, nullptr, nullptr);
    mgemm_k<2><<<SKK / 128, 256, 0, stream>>>(th, tl, nullptr, nullptr, nullptr,
                                              w2th + (size_t)l * HH * HH,
                                              w2tl + (size_t)l * HH * HH,
                                              b2 + l * HH, zh, zl, nullptr,
                                              nullptr, nullptr, nullptr, nullptr,
                                              nullptr, nullptr, nullptr);
    scatter_mean_k<<<NN / 2, 256, 0, stream>>>(zh, zl, node_ptr, rowlist, xah, xal);
    mgemm_k<3><<<SKK / 128, 256, 0, stream>>>(zh, zl, xah, xal, nullptr,
                                              mp2th + (size_t)l * HH * 256,
                                              mp2tl + (size_t)l * HH * 256,
                                              mp2b + l * HH, nullptr, nullptr, uf,
                                              nodes, nullptr, nullptr, nullptr,
                                              nullptr, nullptr, bn_stats + l * 2 * HH);
    bn_finalize_k<<<1, HH, 0, stream>>>(bn_stats + l * 2 * HH, gamma + l * HH,
                                        beta + l * HH, bn_coef + l * 2 * HH);
    bn_apply_k<<<(SKK * HH / 4) / 256, 256, 0, stream>>>(uf, h, bn_coef + l * 2 * HH);
  }
}